// Round 1
// baseline (710.220 us; speedup 1.0000x reference)
//
#include <hip/hip_runtime.h>

#define ELLW 64   // max in-degree capacity (Poisson(16): P(deg>=64) ~ 2e-18)

// ---------------------------------------------------------------------------
// Build ELL adjacency (by dst) + in-degree counts, one pass.
// ---------------------------------------------------------------------------
__global__ __launch_bounds__(256) void build_ell_kernel(
    const int* __restrict__ src, const int* __restrict__ dst, int E,
    int* __restrict__ degi, int* __restrict__ ell)
{
    int e = blockIdx.x * 256 + threadIdx.x;
    if (e >= E) return;
    int d = dst[e];
    int pos = atomicAdd(&degi[d], 1);
    if (pos < ELLW) ell[d * ELLW + pos] = src[e];
}

__global__ __launch_bounds__(256) void dinv_kernel(
    const int* __restrict__ degi, float* __restrict__ dinv, int n)
{
    int i = blockIdx.x * 256 + threadIdx.x;
    if (i >= n) return;
    // reference deg includes self-loop: indeg + 1  (always >= 1)
    dinv[i] = rsqrtf((float)degi[i] + 1.0f);
}

// ---------------------------------------------------------------------------
// FP32 GEMM: out[n][F] = H[n][128] @ W[128][F] (+ bias). No fp32 MFMA on
// CDNA4 -> vector ALU, W + H tiles staged in LDS, 4x8 (or 2x8) reg blocking.
// LDS: sW 64xF + sH 64x68(pad) -> <=50KB -> 3 blocks/CU.
// ---------------------------------------------------------------------------
template<int F, bool BIAS>
__global__ __launch_bounds__(256) void gemm_kernel(
    const float* __restrict__ H, const float* __restrict__ W,
    const float* __restrict__ bias, float* __restrict__ out, int nrows)
{
    constexpr int KH   = 64;   // k-step (two halves of 128)
    constexpr int HPAD = 68;   // 68 % 32 = 4 -> 4-row groups hit banks {b,b+16} (2-way, free)
    constexpr int NCG  = F / 8;           // col groups of 8
    constexpr int MR   = NCG / 4;         // rows per thread (F=128 -> 4, F=64 -> 2)

    __shared__ float sW[KH * F];
    __shared__ float sH[64 * HPAD];

    const int t    = threadIdx.x;
    const int row0 = blockIdx.x * 64;
    const int cg   = t % NCG;
    const int rg   = t / NCG;

    float acc[MR][8];
    #pragma unroll
    for (int m = 0; m < MR; ++m)
        #pragma unroll
        for (int n = 0; n < 8; ++n) acc[m][n] = 0.f;

    for (int kk = 0; kk < 128; kk += KH) {
        __syncthreads();
        // stage W[kk..kk+63][0..F) : KH*F/4 float4s
        #pragma unroll
        for (int i = 0; i < (KH * F / 4) / 256; ++i) {
            int l  = t + i * 256;
            int r  = l / (F / 4);
            int c4 = l % (F / 4);
            *(float4*)&sW[r * F + c4 * 4] =
                *(const float4*)&W[(kk + r) * F + c4 * 4];
        }
        // stage H[row0..row0+63][kk..kk+63]
        #pragma unroll
        for (int i = 0; i < (64 * KH / 4) / 256; ++i) {
            int l   = t + i * 256;
            int r   = l / (KH / 4);
            int c4  = l % (KH / 4);
            int row = row0 + r;
            float4 v = make_float4(0.f, 0.f, 0.f, 0.f);
            if (row < nrows) v = *(const float4*)&H[row * 128 + kk + c4 * 4];
            *(float4*)&sH[r * HPAD + c4 * 4] = v;
        }
        __syncthreads();

        #pragma unroll 8
        for (int k = 0; k < KH; ++k) {
            const float4 w0 = *(const float4*)&sW[k * F + cg * 8];
            const float4 w1 = *(const float4*)&sW[k * F + cg * 8 + 4];
            #pragma unroll
            for (int m = 0; m < MR; ++m) {
                const float hv = sH[(rg * MR + m) * HPAD + k];
                acc[m][0] += hv * w0.x; acc[m][1] += hv * w0.y;
                acc[m][2] += hv * w0.z; acc[m][3] += hv * w0.w;
                acc[m][4] += hv * w1.x; acc[m][5] += hv * w1.y;
                acc[m][6] += hv * w1.z; acc[m][7] += hv * w1.w;
            }
        }
    }

    float b[8];
    if (BIAS) {
        #pragma unroll
        for (int n = 0; n < 8; ++n) b[n] = bias[cg * 8 + n];
    }
    #pragma unroll
    for (int m = 0; m < MR; ++m) {
        int row = row0 + rg * MR + m;
        if (row >= nrows) continue;
        float4 o0, o1;
        o0.x = acc[m][0]; o0.y = acc[m][1]; o0.z = acc[m][2]; o0.w = acc[m][3];
        o1.x = acc[m][4]; o1.y = acc[m][5]; o1.z = acc[m][6]; o1.w = acc[m][7];
        if (BIAS) {
            o0.x += b[0]; o0.y += b[1]; o0.z += b[2]; o0.w += b[3];
            o1.x += b[4]; o1.y += b[5]; o1.z += b[6]; o1.w += b[7];
        }
        *(float4*)&out[row * F + cg * 8]     = o0;
        *(float4*)&out[row * F + cg * 8 + 4] = o1;
    }
}

// ---------------------------------------------------------------------------
// Aggregation (gather form): one wave per node.
//   out[i] = epi( dinv[i] * ( sum_j dinv[j]*hw[j] + dinv[i]*hw[i] ) + bias )
// Lane k prefetches neighbor index + dinv; broadcast via __shfl. Rows of hw
// (512B / 256B) are LLC-resident -> coalesced gather per neighbor.
// ---------------------------------------------------------------------------
template<int F, bool RELU, bool SKIP>
__global__ __launch_bounds__(256) void agg_kernel(
    const float* __restrict__ hw, const int* __restrict__ ell,
    const int* __restrict__ degi, const float* __restrict__ dinv,
    const float* __restrict__ bias, const float* __restrict__ skip,
    float* __restrict__ out, int n)
{
    constexpr int VEC = F / 64;  // 2 for F=128, 1 for F=64
    const int lane = threadIdx.x & 63;
    const int node = blockIdx.x * (256 / 64) + (threadIdx.x >> 6);
    if (node >= n) return;

    const int deg  = degi[node];
    const int kmax = deg < ELLW ? deg : ELLW;
    const float di = dinv[node];

    int   jpre = 0;
    float vpre = 0.f;
    if (lane < kmax) {
        jpre = ell[node * ELLW + lane];
        vpre = dinv[jpre];
    }

    float acc[VEC];
    // self-loop term: dinv[i]*hw[i] (outer di applied at the end -> di^2)
    #pragma unroll
    for (int v = 0; v < VEC; ++v)
        acc[v] = hw[node * F + lane * VEC + v] * di;

    for (int k = 0; k < kmax; ++k) {
        const int   jj = __shfl(jpre, k);
        const float vv = __shfl(vpre, k);
        if (VEC == 2) {
            const float2 h2 = *(const float2*)&hw[jj * F + lane * 2];
            acc[0] += h2.x * vv;
            acc[1] += h2.y * vv;
        } else {
            acc[0] += hw[jj * F + lane] * vv;
        }
    }

    #pragma unroll
    for (int v = 0; v < VEC; ++v) {
        float r = acc[v] * di + bias[lane * VEC + v];
        if (RELU) r = fmaxf(r, 0.f);
        if (SKIP) r += skip[node * F + lane * VEC + v];
        out[node * F + lane * VEC + v] = r;
    }
}

// ---------------------------------------------------------------------------
extern "C" void kernel_launch(void* const* d_in, const int* in_sizes, int n_in,
                              void* d_out, int out_size, void* d_ws, size_t ws_size,
                              hipStream_t stream)
{
    const float* x  = (const float*)d_in[0];
    const int*   ei = (const int*)  d_in[1];
    const float* W0 = (const float*)d_in[2];
    const float* b0 = (const float*)d_in[3];
    const float* W1 = (const float*)d_in[4];
    const float* b1 = (const float*)d_in[5];
    const float* W2 = (const float*)d_in[6];
    const float* b2 = (const float*)d_in[7];
    const float* Ws = (const float*)d_in[8];
    const float* bs = (const float*)d_in[9];

    const int N = in_sizes[0] / 128;
    const int E = in_sizes[1] / 2;
    const int* src = ei;
    const int* dst = ei + E;

    // workspace carve-up (~180 MB total)
    char* ws = (char*)d_ws;
    auto al = [](size_t v) { return (v + 255) & ~size_t(255); };
    size_t off = 0;
    int*   degi = (int*)  (ws + off); off = al(off + (size_t)N * 4);
    float* dinv = (float*)(ws + off); off = al(off + (size_t)N * 4);
    int*   ell  = (int*)  (ws + off); off = al(off + (size_t)N * ELLW * 4);
    float* bufA = (float*)(ws + off); off = al(off + (size_t)N * 128 * 4);
    float* bufB = (float*)(ws + off); off = al(off + (size_t)N * 128 * 4);
    float* bufC = (float*)(ws + off); off = al(off + (size_t)N * 128 * 4);
    (void)ws_size; (void)n_in; (void)out_size;

    hipMemsetAsync(degi, 0, (size_t)N * 4, stream);
    build_ell_kernel<<<(E + 255) / 256, 256, 0, stream>>>(src, dst, E, degi, ell);
    dinv_kernel<<<(N + 255) / 256, 256, 0, stream>>>(degi, dinv, N);

    const int gg = (N + 63) / 64;    // gemm grid
    const int ga = (N + 3) / 4;      // agg grid (4 nodes/block)

    // layer 0: h1 = relu(agg(x@W0) + b0)
    gemm_kernel<128, false><<<gg, 256, 0, stream>>>(x, W0, nullptr, bufA, N);
    agg_kernel<128, true, false><<<ga, 256, 0, stream>>>(bufA, ell, degi, dinv, b0, nullptr, bufB, N);

    // layer 1: h2 = relu(agg(h1@W1) + b1) + (h1@Ws + bs)
    gemm_kernel<128, true ><<<gg, 256, 0, stream>>>(bufB, Ws, bs, bufC, N);
    gemm_kernel<128, false><<<gg, 256, 0, stream>>>(bufB, W1, nullptr, bufA, N);
    agg_kernel<128, true, true><<<ga, 256, 0, stream>>>(bufA, ell, degi, dinv, b1, bufC, bufB, N);

    // output layer: out = agg(h2@W2) + b2   (F=64)
    gemm_kernel<64, false><<<gg, 256, 0, stream>>>(bufB, W2, nullptr, bufA, N);
    agg_kernel<64, false, false><<<ga, 256, 0, stream>>>(bufA, ell, degi, dinv, b2, nullptr, (float*)d_out, N);
}

// Round 2
// 648.922 us; speedup vs baseline: 1.0945x; 1.0945x over previous
//
#include <hip/hip_runtime.h>

#define ELLW 64   // max in-degree capacity (Poisson(16): P(deg>=64) ~ 2e-18)

// ---------------------------------------------------------------------------
// Build ELL adjacency (by dst) + in-degree counts, one pass.
// ---------------------------------------------------------------------------
__global__ __launch_bounds__(256) void build_ell_kernel(
    const int* __restrict__ src, const int* __restrict__ dst, int E,
    int* __restrict__ degi, int* __restrict__ ell)
{
    int e = blockIdx.x * 256 + threadIdx.x;
    if (e >= E) return;
    int d = dst[e];
    int pos = atomicAdd(&degi[d], 1);
    if (pos < ELLW) ell[d * ELLW + pos] = src[e];
}

__global__ __launch_bounds__(256) void dinv_kernel(
    const int* __restrict__ degi, float* __restrict__ dinv, int n)
{
    int i = blockIdx.x * 256 + threadIdx.x;
    if (i >= n) return;
    // reference deg includes self-loop: indeg + 1  (always >= 1)
    dinv[i] = rsqrtf((float)degi[i] + 1.0f);
}

// ---------------------------------------------------------------------------
// FP32 GEMM: out[n][F] = H[n][128] @ W[128][F] (+ bias). No fp32 MFMA on
// CDNA4 -> vector ALU, W + H tiles staged in LDS, 4x8 (or 2x8) reg blocking.
// ---------------------------------------------------------------------------
template<int F, bool BIAS>
__global__ __launch_bounds__(256) void gemm_kernel(
    const float* __restrict__ H, const float* __restrict__ W,
    const float* __restrict__ bias, float* __restrict__ out, int nrows)
{
    constexpr int KH   = 64;   // k-step (two halves of 128)
    constexpr int HPAD = 68;
    constexpr int NCG  = F / 8;           // col groups of 8
    constexpr int MR   = NCG / 4;         // rows per thread (F=128 -> 4, F=64 -> 2)

    __shared__ float sW[KH * F];
    __shared__ float sH[64 * HPAD];

    const int t    = threadIdx.x;
    const int row0 = blockIdx.x * 64;
    const int cg   = t % NCG;
    const int rg   = t / NCG;

    float acc[MR][8];
    #pragma unroll
    for (int m = 0; m < MR; ++m)
        #pragma unroll
        for (int n = 0; n < 8; ++n) acc[m][n] = 0.f;

    for (int kk = 0; kk < 128; kk += KH) {
        __syncthreads();
        // stage W[kk..kk+63][0..F)
        #pragma unroll
        for (int i = 0; i < (KH * F / 4) / 256; ++i) {
            int l  = t + i * 256;
            int r  = l / (F / 4);
            int c4 = l % (F / 4);
            *(float4*)&sW[r * F + c4 * 4] =
                *(const float4*)&W[(kk + r) * F + c4 * 4];
        }
        // stage H[row0..row0+63][kk..kk+63]
        #pragma unroll
        for (int i = 0; i < (64 * KH / 4) / 256; ++i) {
            int l   = t + i * 256;
            int r   = l / (KH / 4);
            int c4  = l % (KH / 4);
            int row = row0 + r;
            float4 v = make_float4(0.f, 0.f, 0.f, 0.f);
            if (row < nrows) v = *(const float4*)&H[row * 128 + kk + c4 * 4];
            *(float4*)&sH[r * HPAD + c4 * 4] = v;
        }
        __syncthreads();

        #pragma unroll 8
        for (int k = 0; k < KH; ++k) {
            const float4 w0 = *(const float4*)&sW[k * F + cg * 8];
            const float4 w1 = *(const float4*)&sW[k * F + cg * 8 + 4];
            #pragma unroll
            for (int m = 0; m < MR; ++m) {
                const float hv = sH[(rg * MR + m) * HPAD + k];
                acc[m][0] += hv * w0.x; acc[m][1] += hv * w0.y;
                acc[m][2] += hv * w0.z; acc[m][3] += hv * w0.w;
                acc[m][4] += hv * w1.x; acc[m][5] += hv * w1.y;
                acc[m][6] += hv * w1.z; acc[m][7] += hv * w1.w;
            }
        }
    }

    float b[8];
    if (BIAS) {
        #pragma unroll
        for (int n = 0; n < 8; ++n) b[n] = bias[cg * 8 + n];
    }
    #pragma unroll
    for (int m = 0; m < MR; ++m) {
        int row = row0 + rg * MR + m;
        if (row >= nrows) continue;
        float4 o0, o1;
        o0.x = acc[m][0]; o0.y = acc[m][1]; o0.z = acc[m][2]; o0.w = acc[m][3];
        o1.x = acc[m][4]; o1.y = acc[m][5]; o1.z = acc[m][6]; o1.w = acc[m][7];
        if (BIAS) {
            o0.x += b[0]; o0.y += b[1]; o0.z += b[2]; o0.w += b[3];
            o1.x += b[4]; o1.y += b[5]; o1.z += b[6]; o1.w += b[7];
        }
        *(float4*)&out[row * F + cg * 8]     = o0;
        *(float4*)&out[row * F + cg * 8 + 4] = o1;
    }
}

// ---------------------------------------------------------------------------
// Aggregation (gather form): one wave per node, 8-way unrolled gather for MLP.
//   out[i] = epi( dinv[i] * ( sum_j dinv[j]*hw[j] + dinv[i]*hw[i] ) + bias )
// Lanes >= deg hold {jpre=0, vpre=0}, so kmax is rounded UP to a multiple of
// UNR: dummy iterations gather row 0 (cache-hot) and multiply by 0 -> no
// serial tail, 8 loads in flight per wave.
// ---------------------------------------------------------------------------
template<int F, bool RELU, bool SKIP>
__global__ __launch_bounds__(256) void agg_kernel(
    const float* __restrict__ hw, const int* __restrict__ ell,
    const int* __restrict__ degi, const float* __restrict__ dinv,
    const float* __restrict__ bias, const float* __restrict__ skip,
    float* __restrict__ out, int n)
{
    constexpr int VEC = F / 64;  // 2 for F=128, 1 for F=64
    constexpr int UNR = 8;
    const int lane = threadIdx.x & 63;
    const int node = blockIdx.x * (256 / 64) + (threadIdx.x >> 6);
    if (node >= n) return;

    const int deg  = degi[node];
    const int kmax = deg < ELLW ? deg : ELLW;
    const float di = dinv[node];

    int   jpre = 0;
    float vpre = 0.f;
    if (lane < kmax) {
        jpre = ell[node * ELLW + lane];
        vpre = dinv[jpre];
    }

    // 4 independent accumulator sets (break the FMA chain)
    float acc[4][VEC];
    #pragma unroll
    for (int u = 0; u < 4; ++u)
        #pragma unroll
        for (int v = 0; v < VEC; ++v) acc[u][v] = 0.f;

    // self-loop term: dinv[i]*hw[i] (outer di applied at the end -> di^2)
    #pragma unroll
    for (int v = 0; v < VEC; ++v)
        acc[0][v] = hw[node * F + lane * VEC + v] * di;

    const int kceil = (kmax + UNR - 1) & ~(UNR - 1);   // <= ELLW = 64
    for (int k = 0; k < kceil; k += UNR) {
        int   jj[UNR];
        float vv[UNR];
        #pragma unroll
        for (int u = 0; u < UNR; ++u) {
            jj[u] = __shfl(jpre, k + u);
            vv[u] = __shfl(vpre, k + u);
        }
        if constexpr (VEC == 2) {
            float2 h[UNR];
            #pragma unroll
            for (int u = 0; u < UNR; ++u)
                h[u] = *(const float2*)&hw[jj[u] * F + lane * 2];
            #pragma unroll
            for (int u = 0; u < UNR; ++u) {
                acc[u & 3][0] += h[u].x * vv[u];
                acc[u & 3][1] += h[u].y * vv[u];
            }
        } else {
            float h[UNR];
            #pragma unroll
            for (int u = 0; u < UNR; ++u)
                h[u] = hw[jj[u] * F + lane];
            #pragma unroll
            for (int u = 0; u < UNR; ++u)
                acc[u & 3][0] += h[u] * vv[u];
        }
    }

    #pragma unroll
    for (int v = 0; v < VEC; ++v) {
        float s = (acc[0][v] + acc[1][v]) + (acc[2][v] + acc[3][v]);
        float r = s * di + bias[lane * VEC + v];
        if (RELU) r = fmaxf(r, 0.f);
        if (SKIP) r += skip[node * F + lane * VEC + v];
        out[node * F + lane * VEC + v] = r;
    }
}

// ---------------------------------------------------------------------------
extern "C" void kernel_launch(void* const* d_in, const int* in_sizes, int n_in,
                              void* d_out, int out_size, void* d_ws, size_t ws_size,
                              hipStream_t stream)
{
    const float* x  = (const float*)d_in[0];
    const int*   ei = (const int*)  d_in[1];
    const float* W0 = (const float*)d_in[2];
    const float* b0 = (const float*)d_in[3];
    const float* W1 = (const float*)d_in[4];
    const float* b1 = (const float*)d_in[5];
    const float* W2 = (const float*)d_in[6];
    const float* b2 = (const float*)d_in[7];
    const float* Ws = (const float*)d_in[8];
    const float* bs = (const float*)d_in[9];

    const int N = in_sizes[0] / 128;
    const int E = in_sizes[1] / 2;
    const int* src = ei;
    const int* dst = ei + E;

    // workspace carve-up (~180 MB total)
    char* ws = (char*)d_ws;
    auto al = [](size_t v) { return (v + 255) & ~size_t(255); };
    size_t off = 0;
    int*   degi = (int*)  (ws + off); off = al(off + (size_t)N * 4);
    float* dinv = (float*)(ws + off); off = al(off + (size_t)N * 4);
    int*   ell  = (int*)  (ws + off); off = al(off + (size_t)N * ELLW * 4);
    float* bufA = (float*)(ws + off); off = al(off + (size_t)N * 128 * 4);
    float* bufB = (float*)(ws + off); off = al(off + (size_t)N * 128 * 4);
    float* bufC = (float*)(ws + off); off = al(off + (size_t)N * 128 * 4);
    (void)ws_size; (void)n_in; (void)out_size;

    hipMemsetAsync(degi, 0, (size_t)N * 4, stream);
    build_ell_kernel<<<(E + 255) / 256, 256, 0, stream>>>(src, dst, E, degi, ell);
    dinv_kernel<<<(N + 255) / 256, 256, 0, stream>>>(degi, dinv, N);

    const int gg = (N + 63) / 64;    // gemm grid
    const int ga = (N + 3) / 4;      // agg grid (4 nodes/block)

    // layer 0: h1 = relu(agg(x@W0) + b0)
    gemm_kernel<128, false><<<gg, 256, 0, stream>>>(x, W0, nullptr, bufA, N);
    agg_kernel<128, true, false><<<ga, 256, 0, stream>>>(bufA, ell, degi, dinv, b0, nullptr, bufB, N);

    // layer 1: h2 = relu(agg(h1@W1) + b1) + (h1@Ws + bs)
    gemm_kernel<128, true ><<<gg, 256, 0, stream>>>(bufB, Ws, bs, bufC, N);
    gemm_kernel<128, false><<<gg, 256, 0, stream>>>(bufB, W1, nullptr, bufA, N);
    agg_kernel<128, true, true><<<ga, 256, 0, stream>>>(bufA, ell, degi, dinv, b1, bufC, bufB, N);

    // output layer: out = agg(h2@W2) + b2   (F=64)
    gemm_kernel<64, false><<<gg, 256, 0, stream>>>(bufB, W2, nullptr, bufA, N);
    agg_kernel<64, false, false><<<ga, 256, 0, stream>>>(bufA, ell, degi, dinv, b2, nullptr, (float*)d_out, N);
}

// Round 3
// 562.535 us; speedup vs baseline: 1.2625x; 1.1536x over previous
//
#include <hip/hip_runtime.h>

#define ELLW 64   // max in-degree capacity (Poisson(16): P(deg>=64) ~ 2e-18)

typedef __attribute__((ext_vector_type(8))) short short8v;  // 8 bf16 (4 VGPR)
typedef __attribute__((ext_vector_type(4))) float f32x4;    // MFMA accumulator

__device__ inline unsigned short bf16_rne(float x) {
    unsigned u = __float_as_uint(x);
    u += 0x7FFFu + ((u >> 16) & 1u);
    return (unsigned short)(u >> 16);
}
__device__ inline float bf16_to_f32(unsigned short h) {
    return __uint_as_float(((unsigned)h) << 16);
}

// ---------------------------------------------------------------------------
// Build ELL adjacency (by dst) + in-degree counts, one pass.
// ---------------------------------------------------------------------------
__global__ __launch_bounds__(256) void build_ell_kernel(
    const int* __restrict__ src, const int* __restrict__ dst, int E,
    int* __restrict__ degi, int* __restrict__ ell)
{
    int e = blockIdx.x * 256 + threadIdx.x;
    if (e >= E) return;
    int d = dst[e];
    int pos = atomicAdd(&degi[d], 1);
    if (pos < ELLW) ell[d * ELLW + pos] = src[e];
}

__global__ __launch_bounds__(256) void dinv_kernel(
    const int* __restrict__ degi, float* __restrict__ dinv, int n)
{
    int i = blockIdx.x * 256 + threadIdx.x;
    if (i >= n) return;
    dinv[i] = rsqrtf((float)degi[i] + 1.0f);  // deg includes self-loop
}

// ---------------------------------------------------------------------------
// One-time W preprocess: split fp32 W[K=128][F] into bf16 hi/lo planes,
// stored TRANSPOSED [F][128] so GEMM B-fragments are contiguous 16B reads.
// ---------------------------------------------------------------------------
__global__ __launch_bounds__(256) void split_w_kernel(
    const float* __restrict__ W, unsigned short* __restrict__ WhiT,
    unsigned short* __restrict__ WloT, int F)
{
    int id = blockIdx.x * 256 + threadIdx.x;     // over 128*F
    if (id >= 128 * F) return;
    int k = id / F, c = id % F;
    float x = W[id];
    unsigned short hi = bf16_rne(x);
    float lo = x - bf16_to_f32(hi);
    WhiT[c * 128 + k] = hi;
    WloT[c * 128 + k] = bf16_rne(lo);
}

// ---------------------------------------------------------------------------
// Split-bf16 MFMA GEMM: out[N x F] = H[N x 128] @ W[128 x F] (+ bias).
// fp32 via 3-term split: H_hi*W_hi + H_hi*W_lo + H_lo*W_hi (fp32 acc).
// Block: 256 thr = 4 waves (2x2), tile 128 rows x F cols.
// Wave tile: 64 rows (4 m-frags) x F/2 cols (F/32 cg) of 16x16x32 MFMA.
// LDS: H hi/lo [128][128] bf16 (64 KB, staged once, XOR-swizzled) +
//      W hi/lo [F][32] bf16 per k-step (16/8 KB) -> 2 blocks/CU.
// ---------------------------------------------------------------------------
template<int F, bool BIAS>
__global__ __launch_bounds__(256) void mfma_gemm_kernel(
    const float* __restrict__ H, const unsigned short* __restrict__ WhiT,
    const unsigned short* __restrict__ WloT, const float* __restrict__ bias,
    float* __restrict__ out, int nrows)
{
    constexpr int NCGW = F / 32;   // col-groups of 16 per wave (2x2 wave grid)

    __shared__ unsigned short sHhi[128 * 128];
    __shared__ unsigned short sHlo[128 * 128];
    __shared__ unsigned short sWhi[F * 32];
    __shared__ unsigned short sWlo[F * 32];

    const int t    = threadIdx.x;
    const int lane = t & 63;
    const int wv   = t >> 6;
    const int wm   = wv >> 1, wn = wv & 1;
    const int row0 = blockIdx.x * 128;
    const int l15  = lane & 15;
    const int lg   = lane >> 4;

    // ---- stage H, split to bf16 hi/lo (swizzle: byte ^= (row&7)<<4) ----
    #pragma unroll
    for (int i = 0; i < 8; ++i) {
        int id = t + i * 256;          // 2048 chunks of 8 elems
        int r  = id >> 4;
        int kc = id & 15;
        int row = row0 + r;
        float4 v0 = make_float4(0.f, 0.f, 0.f, 0.f), v1 = v0;
        if (row < nrows) {
            v0 = *(const float4*)&H[(size_t)row * 128 + kc * 8];
            v1 = *(const float4*)&H[(size_t)row * 128 + kc * 8 + 4];
        }
        float xs[8] = {v0.x, v0.y, v0.z, v0.w, v1.x, v1.y, v1.z, v1.w};
        short8v hv, lv;
        #pragma unroll
        for (int j = 0; j < 8; ++j) {
            unsigned short h = bf16_rne(xs[j]);
            hv[j] = (short)h;
            lv[j] = (short)bf16_rne(xs[j] - bf16_to_f32(h));
        }
        int bo = (r * 256 + kc * 16) ^ ((r & 7) << 4);
        *(short8v*)((char*)sHhi + bo) = hv;
        *(short8v*)((char*)sHlo + bo) = lv;
    }

    f32x4 acc[4][NCGW];
    #pragma unroll
    for (int mf = 0; mf < 4; ++mf)
        #pragma unroll
        for (int cg = 0; cg < NCGW; ++cg)
            acc[mf][cg] = (f32x4){0.f, 0.f, 0.f, 0.f};

    for (int kk = 0; kk < 4; ++kk) {
        __syncthreads();
        // stage W k-slice [F][32] hi/lo (swizzle byte ^= (col&7)<<4)
        #pragma unroll
        for (int i = 0; i < (F * 4) / 256; ++i) {
            int id = t + i * 256;
            int c = id >> 2, g = id & 3;
            short8v vh = *(const short8v*)&WhiT[c * 128 + kk * 32 + g * 8];
            short8v vl = *(const short8v*)&WloT[c * 128 + kk * 32 + g * 8];
            int bo = (c * 64 + g * 16) ^ ((c & 7) << 4);
            *(short8v*)((char*)sWhi + bo) = vh;
            *(short8v*)((char*)sWlo + bo) = vl;
        }
        __syncthreads();

        // A fragments: 4 m-frags x {hi,lo}
        short8v ahi[4], alo[4];
        #pragma unroll
        for (int mf = 0; mf < 4; ++mf) {
            int row = wm * 64 + mf * 16 + l15;
            int bo = (row * 256 + kk * 64 + lg * 16) ^ ((row & 7) << 4);
            ahi[mf] = *(short8v*)((char*)sHhi + bo);
            alo[mf] = *(short8v*)((char*)sHlo + bo);
        }
        #pragma unroll
        for (int cg = 0; cg < NCGW; ++cg) {
            int col = wn * (F / 2) + cg * 16 + l15;
            int bo = (col * 64 + lg * 16) ^ ((col & 7) << 4);
            short8v bhi = *(short8v*)((char*)sWhi + bo);
            short8v blo = *(short8v*)((char*)sWlo + bo);
            #pragma unroll
            for (int mf = 0; mf < 4; ++mf) {
                acc[mf][cg] = __builtin_amdgcn_mfma_f32_16x16x32_bf16(ahi[mf], bhi, acc[mf][cg], 0, 0, 0);
                acc[mf][cg] = __builtin_amdgcn_mfma_f32_16x16x32_bf16(ahi[mf], blo, acc[mf][cg], 0, 0, 0);
                acc[mf][cg] = __builtin_amdgcn_mfma_f32_16x16x32_bf16(alo[mf], bhi, acc[mf][cg], 0, 0, 0);
            }
        }
    }

    // epilogue: C/D layout col=lane&15, row=(lane>>4)*4+reg (m89-verified)
    #pragma unroll
    for (int cg = 0; cg < NCGW; ++cg) {
        int col = wn * (F / 2) + cg * 16 + l15;
        float bv = BIAS ? bias[col] : 0.f;
        #pragma unroll
        for (int mf = 0; mf < 4; ++mf) {
            int rbase = row0 + wm * 64 + mf * 16 + lg * 4;
            #pragma unroll
            for (int r = 0; r < 4; ++r) {
                int row = rbase + r;
                if (row < nrows) out[(size_t)row * F + col] = acc[mf][cg][r] + bv;
            }
        }
    }
}

// ---------------------------------------------------------------------------
// Aggregation (gather form): one wave per node, 8-way unrolled gather.
//   out[i] = epi( dinv[i] * ( sum_j dinv[j]*hw[j] + dinv[i]*hw[i] ) + bias )
// ---------------------------------------------------------------------------
template<int F, bool RELU, bool SKIP>
__global__ __launch_bounds__(256) void agg_kernel(
    const float* __restrict__ hw, const int* __restrict__ ell,
    const int* __restrict__ degi, const float* __restrict__ dinv,
    const float* __restrict__ bias, const float* __restrict__ skip,
    float* __restrict__ out, int n)
{
    constexpr int VEC = F / 64;
    constexpr int UNR = 8;
    const int lane = threadIdx.x & 63;
    const int node = blockIdx.x * (256 / 64) + (threadIdx.x >> 6);
    if (node >= n) return;

    const int deg  = degi[node];
    const int kmax = deg < ELLW ? deg : ELLW;
    const float di = dinv[node];

    int   jpre = 0;
    float vpre = 0.f;
    if (lane < kmax) {
        jpre = ell[node * ELLW + lane];
        vpre = dinv[jpre];
    }

    float acc[4][VEC];
    #pragma unroll
    for (int u = 0; u < 4; ++u)
        #pragma unroll
        for (int v = 0; v < VEC; ++v) acc[u][v] = 0.f;

    #pragma unroll
    for (int v = 0; v < VEC; ++v)
        acc[0][v] = hw[node * F + lane * VEC + v] * di;

    const int kceil = (kmax + UNR - 1) & ~(UNR - 1);
    for (int k = 0; k < kceil; k += UNR) {
        int   jj[UNR];
        float vv[UNR];
        #pragma unroll
        for (int u = 0; u < UNR; ++u) {
            jj[u] = __shfl(jpre, k + u);
            vv[u] = __shfl(vpre, k + u);
        }
        if constexpr (VEC == 2) {
            float2 h[UNR];
            #pragma unroll
            for (int u = 0; u < UNR; ++u)
                h[u] = *(const float2*)&hw[jj[u] * F + lane * 2];
            #pragma unroll
            for (int u = 0; u < UNR; ++u) {
                acc[u & 3][0] += h[u].x * vv[u];
                acc[u & 3][1] += h[u].y * vv[u];
            }
        } else {
            float h[UNR];
            #pragma unroll
            for (int u = 0; u < UNR; ++u)
                h[u] = hw[jj[u] * F + lane];
            #pragma unroll
            for (int u = 0; u < UNR; ++u)
                acc[u & 3][0] += h[u] * vv[u];
        }
    }

    #pragma unroll
    for (int v = 0; v < VEC; ++v) {
        float s = (acc[0][v] + acc[1][v]) + (acc[2][v] + acc[3][v]);
        float r = s * di + bias[lane * VEC + v];
        if (RELU) r = fmaxf(r, 0.f);
        if (SKIP) r += skip[node * F + lane * VEC + v];
        out[node * F + lane * VEC + v] = r;
    }
}

// ---------------------------------------------------------------------------
extern "C" void kernel_launch(void* const* d_in, const int* in_sizes, int n_in,
                              void* d_out, int out_size, void* d_ws, size_t ws_size,
                              hipStream_t stream)
{
    const float* x  = (const float*)d_in[0];
    const int*   ei = (const int*)  d_in[1];
    const float* W0 = (const float*)d_in[2];
    const float* b0 = (const float*)d_in[3];
    const float* W1 = (const float*)d_in[4];
    const float* b1 = (const float*)d_in[5];
    const float* W2 = (const float*)d_in[6];
    const float* b2 = (const float*)d_in[7];
    const float* Ws = (const float*)d_in[8];
    const float* bs = (const float*)d_in[9];

    const int N = in_sizes[0] / 128;
    const int E = in_sizes[1] / 2;
    const int* src = ei;
    const int* dst = ei + E;

    char* ws = (char*)d_ws;
    auto al = [](size_t v) { return (v + 255) & ~size_t(255); };
    size_t off = 0;
    int*   degi = (int*)  (ws + off); off = al(off + (size_t)N * 4);
    float* dinv = (float*)(ws + off); off = al(off + (size_t)N * 4);
    int*   ell  = (int*)  (ws + off); off = al(off + (size_t)N * ELLW * 4);
    float* bufA = (float*)(ws + off); off = al(off + (size_t)N * 128 * 4);
    float* bufB = (float*)(ws + off); off = al(off + (size_t)N * 128 * 4);
    float* bufC = (float*)(ws + off); off = al(off + (size_t)N * 128 * 4);
    unsigned short* W0hi = (unsigned short*)(ws + off); off = al(off + 128 * 128 * 2);
    unsigned short* W0lo = (unsigned short*)(ws + off); off = al(off + 128 * 128 * 2);
    unsigned short* W1hi = (unsigned short*)(ws + off); off = al(off + 128 * 128 * 2);
    unsigned short* W1lo = (unsigned short*)(ws + off); off = al(off + 128 * 128 * 2);
    unsigned short* Wshi = (unsigned short*)(ws + off); off = al(off + 128 * 128 * 2);
    unsigned short* Wslo = (unsigned short*)(ws + off); off = al(off + 128 * 128 * 2);
    unsigned short* W2hi = (unsigned short*)(ws + off); off = al(off + 128 * 64 * 2);
    unsigned short* W2lo = (unsigned short*)(ws + off); off = al(off + 128 * 64 * 2);
    (void)ws_size; (void)n_in; (void)out_size;

    hipMemsetAsync(degi, 0, (size_t)N * 4, stream);
    build_ell_kernel<<<(E + 255) / 256, 256, 0, stream>>>(src, dst, E, degi, ell);
    dinv_kernel<<<(N + 255) / 256, 256, 0, stream>>>(degi, dinv, N);
    split_w_kernel<<<64, 256, 0, stream>>>(W0, W0hi, W0lo, 128);
    split_w_kernel<<<64, 256, 0, stream>>>(W1, W1hi, W1lo, 128);
    split_w_kernel<<<64, 256, 0, stream>>>(Ws, Wshi, Wslo, 128);
    split_w_kernel<<<32, 256, 0, stream>>>(W2, W2hi, W2lo, 64);

    const int gg = (N + 127) / 128;  // mfma gemm grid
    const int ga = (N + 3) / 4;      // agg grid (4 nodes/block)

    // layer 0: h1 = relu(agg(x@W0) + b0)
    mfma_gemm_kernel<128, false><<<gg, 256, 0, stream>>>(x, W0hi, W0lo, nullptr, bufA, N);
    agg_kernel<128, true, false><<<ga, 256, 0, stream>>>(bufA, ell, degi, dinv, b0, nullptr, bufB, N);

    // layer 1: h2 = relu(agg(h1@W1) + b1) + (h1@Ws + bs)
    mfma_gemm_kernel<128, true ><<<gg, 256, 0, stream>>>(bufB, Wshi, Wslo, bs, bufC, N);
    mfma_gemm_kernel<128, false><<<gg, 256, 0, stream>>>(bufB, W1hi, W1lo, nullptr, bufA, N);
    agg_kernel<128, true, true><<<ga, 256, 0, stream>>>(bufA, ell, degi, dinv, b1, bufC, bufB, N);

    // output layer: out = agg(h2@W2) + b2   (F=64)
    mfma_gemm_kernel<64, false><<<gg, 256, 0, stream>>>(bufB, W2hi, W2lo, nullptr, bufA, N);
    agg_kernel<64, false, false><<<ga, 256, 0, stream>>>(bufA, ell, degi, dinv, b2, nullptr, (float*)d_out, N);
}

// Round 4
// 464.096 us; speedup vs baseline: 1.5303x; 1.2121x over previous
//
#include <hip/hip_runtime.h>

#define ELLW 64   // max in-degree capacity (Poisson(16): P(deg>=64) ~ 2e-18)

typedef __attribute__((ext_vector_type(8))) short short8v;  // 8 bf16 (4 VGPR)
typedef __attribute__((ext_vector_type(4))) float f32x4;    // MFMA accumulator

__device__ inline unsigned short bf16_rne(float x) {
    unsigned u = __float_as_uint(x);
    u += 0x7FFFu + ((u >> 16) & 1u);
    return (unsigned short)(u >> 16);
}
__device__ inline float bf16_to_f32(unsigned short h) {
    return __uint_as_float(((unsigned)h) << 16);
}

// ---------------------------------------------------------------------------
// Build ELL adjacency (by dst) + in-degree counts, one pass.
// ---------------------------------------------------------------------------
__global__ __launch_bounds__(256) void build_ell_kernel(
    const int* __restrict__ src, const int* __restrict__ dst, int E,
    int* __restrict__ degi, int* __restrict__ ell)
{
    int e = blockIdx.x * 256 + threadIdx.x;
    if (e >= E) return;
    int d = dst[e];
    int pos = atomicAdd(&degi[d], 1);
    if (pos < ELLW) ell[d * ELLW + pos] = src[e];
}

__global__ __launch_bounds__(256) void dinv_kernel(
    const int* __restrict__ degi, float* __restrict__ dinv, int n)
{
    int i = blockIdx.x * 256 + threadIdx.x;
    if (i >= n) return;
    dinv[i] = rsqrtf((float)degi[i] + 1.0f);  // deg includes self-loop
}

// ---------------------------------------------------------------------------
// One-time W preprocess: split fp32 W[128][F] into bf16 hi/lo planes,
// stored TRANSPOSED [F][128] so B-fragments are contiguous 16B loads.
// ---------------------------------------------------------------------------
__global__ __launch_bounds__(256) void split_w_kernel(
    const float* __restrict__ W, unsigned short* __restrict__ WhiT,
    unsigned short* __restrict__ WloT, int F)
{
    int id = blockIdx.x * 256 + threadIdx.x;     // over 128*F
    if (id >= 128 * F) return;
    int k = id / F, c = id % F;
    float x = W[id];
    unsigned short hi = bf16_rne(x);
    WhiT[c * 128 + k] = hi;
    WloT[c * 128 + k] = bf16_rne(x - bf16_to_f32(hi));
}

// ---------------------------------------------------------------------------
// LDS-free split-bf16 MFMA GEMM: out_bf16[N x F] = A[N x 128] @ W[128 x F] (+bias)
// A source: fp32 (layer 0, split in-register) or pre-split bf16 hi/lo planes.
// 3-term: Ahi*Bhi + Ahi*Blo + Alo*Bhi, fp32 accum. No LDS, no barriers:
// fragments loaded straight from global (A tile 64KB and W 32KB are L1/L2-hot).
// Block 256 thr = 4 waves; F=128: 2x2 waves (64r x 64c each); F=64: 4x1
// (32r x 64c). Block tile = 128 rows.
// ---------------------------------------------------------------------------
template<int F, bool AFP32, bool BIAS>
__global__ __launch_bounds__(256) void mfma_gemm_kernel(
    const float* __restrict__ Af,
    const unsigned short* __restrict__ Ahi, const unsigned short* __restrict__ Alo,
    const unsigned short* __restrict__ BhiT, const unsigned short* __restrict__ BloT,
    const float* __restrict__ bias, unsigned short* __restrict__ out, int nrows)
{
    constexpr int WM = (F == 128) ? 2 : 4;     // wave grid rows
    constexpr int MF = 128 / (WM * 16);        // m-frags per wave (4 or 2)
    constexpr int CG = 4;                      // col-frags per wave (64 cols)

    const int t    = threadIdx.x;
    const int lane = t & 63;
    const int wv   = t >> 6;
    const int wm   = (F == 128) ? (wv >> 1) : wv;
    const int wn   = (F == 128) ? (wv & 1)  : 0;
    const int l15  = lane & 15;
    const int lg   = lane >> 4;
    const int row0 = blockIdx.x * 128;

    f32x4 acc[MF][CG];
    #pragma unroll
    for (int mf = 0; mf < MF; ++mf)
        #pragma unroll
        for (int cg = 0; cg < CG; ++cg)
            acc[mf][cg] = (f32x4){0.f, 0.f, 0.f, 0.f};

    #pragma unroll
    for (int kk = 0; kk < 4; ++kk) {
        short8v ah[MF], al[MF];
        #pragma unroll
        for (int mf = 0; mf < MF; ++mf) {
            int row = row0 + wm * (MF * 16) + mf * 16 + l15;
            int rl  = row < nrows ? row : 0;
            size_t ao = (size_t)rl * 128 + kk * 32 + lg * 8;
            if constexpr (AFP32) {
                const float* p = &Af[ao];
                float4 v0 = *(const float4*)p;
                float4 v1 = *(const float4*)(p + 4);
                float xs[8] = {v0.x, v0.y, v0.z, v0.w, v1.x, v1.y, v1.z, v1.w};
                short8v h, l;
                #pragma unroll
                for (int j = 0; j < 8; ++j) {
                    unsigned short hb = bf16_rne(xs[j]);
                    h[j] = (short)hb;
                    l[j] = (short)bf16_rne(xs[j] - bf16_to_f32(hb));
                }
                ah[mf] = h; al[mf] = l;
            } else {
                ah[mf] = *(const short8v*)&Ahi[ao];
                al[mf] = *(const short8v*)&Alo[ao];
            }
        }
        #pragma unroll
        for (int cg = 0; cg < CG; ++cg) {
            int col = wn * 64 + cg * 16 + l15;
            size_t bo = (size_t)col * 128 + kk * 32 + lg * 8;
            short8v bh = *(const short8v*)&BhiT[bo];
            short8v bl = *(const short8v*)&BloT[bo];
            #pragma unroll
            for (int mf = 0; mf < MF; ++mf) {
                acc[mf][cg] = __builtin_amdgcn_mfma_f32_16x16x32_bf16(ah[mf], bh, acc[mf][cg], 0, 0, 0);
                acc[mf][cg] = __builtin_amdgcn_mfma_f32_16x16x32_bf16(ah[mf], bl, acc[mf][cg], 0, 0, 0);
                acc[mf][cg] = __builtin_amdgcn_mfma_f32_16x16x32_bf16(al[mf], bh, acc[mf][cg], 0, 0, 0);
            }
        }
    }

    // epilogue: C/D layout col=lane&15, row=(lane>>4)*4+reg; write bf16
    #pragma unroll
    for (int cg = 0; cg < CG; ++cg) {
        int col = wn * 64 + cg * 16 + l15;
        float bv = BIAS ? bias[col] : 0.f;
        #pragma unroll
        for (int mf = 0; mf < MF; ++mf) {
            int rbase = row0 + wm * (MF * 16) + mf * 16 + lg * 4;
            #pragma unroll
            for (int r = 0; r < 4; ++r) {
                int row = rbase + r;
                if (row < nrows)
                    out[(size_t)row * F + col] = bf16_rne(acc[mf][cg][r] + bv);
            }
        }
    }
}

// ---------------------------------------------------------------------------
// Aggregation over bf16 rows, one wave per node, 8-way unrolled gather.
//   r = dinv_i * ( sum_j dinv_j*hw_j + dinv_i*hw_i ) + bias
// MODE 0: relu(r)            -> bf16 hi/lo planes   (h1)
// MODE 1: relu(r) + skip     -> bf16 hi/lo planes   (h2)
// MODE 2: r                  -> fp32 d_out          (F=64 output layer)
// ---------------------------------------------------------------------------
template<int F, int MODE>
__global__ __launch_bounds__(256) void agg_kernel(
    const unsigned short* __restrict__ hw, const int* __restrict__ ell,
    const int* __restrict__ degi, const float* __restrict__ dinv,
    const float* __restrict__ bias, const unsigned short* __restrict__ skip,
    unsigned* __restrict__ outHi, unsigned* __restrict__ outLo,
    float* __restrict__ outF, int n)
{
    constexpr int VEC = F / 64;  // 2 for F=128, 1 for F=64
    constexpr int UNR = 8;
    const int lane = threadIdx.x & 63;
    const int node = blockIdx.x * 4 + (threadIdx.x >> 6);
    if (node >= n) return;

    const int deg  = degi[node];
    const int kmax = deg < ELLW ? deg : ELLW;
    const float di = dinv[node];

    int   jpre = 0;
    float vpre = 0.f;
    if (lane < kmax) {
        jpre = ell[node * ELLW + lane];
        vpre = dinv[jpre];
    }

    float acc[4][VEC];
    #pragma unroll
    for (int u = 0; u < 4; ++u)
        #pragma unroll
        for (int v = 0; v < VEC; ++v) acc[u][v] = 0.f;

    // self-loop term (outer di applied at end -> di^2)
    if constexpr (VEC == 2) {
        unsigned p = *(const unsigned*)&hw[(size_t)node * F + lane * 2];
        acc[0][0] = bf16_to_f32((unsigned short)(p & 0xFFFF)) * di;
        acc[0][1] = bf16_to_f32((unsigned short)(p >> 16)) * di;
    } else {
        acc[0][0] = bf16_to_f32(hw[(size_t)node * F + lane]) * di;
    }

    const int kceil = (kmax + UNR - 1) & ~(UNR - 1);
    for (int k = 0; k < kceil; k += UNR) {
        int   jj[UNR];
        float vv[UNR];
        #pragma unroll
        for (int u = 0; u < UNR; ++u) {
            jj[u] = __shfl(jpre, k + u);
            vv[u] = __shfl(vpre, k + u);
        }
        if constexpr (VEC == 2) {
            unsigned h[UNR];
            #pragma unroll
            for (int u = 0; u < UNR; ++u)
                h[u] = *(const unsigned*)&hw[(size_t)jj[u] * F + lane * 2];
            #pragma unroll
            for (int u = 0; u < UNR; ++u) {
                acc[u & 3][0] += bf16_to_f32((unsigned short)(h[u] & 0xFFFF)) * vv[u];
                acc[u & 3][1] += bf16_to_f32((unsigned short)(h[u] >> 16)) * vv[u];
            }
        } else {
            unsigned short h[UNR];
            #pragma unroll
            for (int u = 0; u < UNR; ++u)
                h[u] = hw[(size_t)jj[u] * F + lane];
            #pragma unroll
            for (int u = 0; u < UNR; ++u)
                acc[u & 3][0] += bf16_to_f32(h[u]) * vv[u];
        }
    }

    float r[VEC];
    #pragma unroll
    for (int v = 0; v < VEC; ++v) {
        float s = (acc[0][v] + acc[1][v]) + (acc[2][v] + acc[3][v]);
        r[v] = s * di + bias[lane * VEC + v];
    }

    if constexpr (MODE == 2) {
        outF[(size_t)node * F + lane] = r[0];
    } else {
        #pragma unroll
        for (int v = 0; v < VEC; ++v) {
            r[v] = fmaxf(r[v], 0.f);
            if (MODE == 1) {
                unsigned sp = *(const unsigned*)&skip[(size_t)node * F + lane * 2];
                float sv = (v == 0) ? bf16_to_f32((unsigned short)(sp & 0xFFFF))
                                    : bf16_to_f32((unsigned short)(sp >> 16));
                r[v] += sv;
            }
        }
        // write hi/lo bf16 plane pair (full fp32 fidelity for downstream GEMM)
        unsigned short h0 = bf16_rne(r[0]), h1 = bf16_rne(r[1]);
        unsigned short l0 = bf16_rne(r[0] - bf16_to_f32(h0));
        unsigned short l1 = bf16_rne(r[1] - bf16_to_f32(h1));
        size_t o = (size_t)node * (F / 2) + lane;
        outHi[o] = (unsigned)h0 | ((unsigned)h1 << 16);
        outLo[o] = (unsigned)l0 | ((unsigned)l1 << 16);
    }
}

// ---------------------------------------------------------------------------
extern "C" void kernel_launch(void* const* d_in, const int* in_sizes, int n_in,
                              void* d_out, int out_size, void* d_ws, size_t ws_size,
                              hipStream_t stream)
{
    const float* x  = (const float*)d_in[0];
    const int*   ei = (const int*)  d_in[1];
    const float* W0 = (const float*)d_in[2];
    const float* b0 = (const float*)d_in[3];
    const float* W1 = (const float*)d_in[4];
    const float* b1 = (const float*)d_in[5];
    const float* W2 = (const float*)d_in[6];
    const float* b2 = (const float*)d_in[7];
    const float* Ws = (const float*)d_in[8];
    const float* bs = (const float*)d_in[9];

    const int N = in_sizes[0] / 128;
    const int E = in_sizes[1] / 2;
    const int* src = ei;
    const int* dst = ei + E;

    char* ws = (char*)d_ws;
    auto al = [](size_t v) { return (v + 255) & ~size_t(255); };
    size_t off = 0;
    int*   degi = (int*)  (ws + off); off = al(off + (size_t)N * 4);
    float* dinv = (float*)(ws + off); off = al(off + (size_t)N * 4);
    int*   ell  = (int*)  (ws + off); off = al(off + (size_t)N * ELLW * 4);
    unsigned short* pA   = (unsigned short*)(ws + off); off = al(off + (size_t)N * 128 * 2);  // hw plane
    unsigned short* pBhi = (unsigned short*)(ws + off); off = al(off + (size_t)N * 128 * 2);  // h hi
    unsigned short* pBlo = (unsigned short*)(ws + off); off = al(off + (size_t)N * 128 * 2);  // h lo
    unsigned short* pC   = (unsigned short*)(ws + off); off = al(off + (size_t)N * 128 * 2);  // skip
    unsigned short* W0hi = (unsigned short*)(ws + off); off = al(off + 128 * 128 * 2);
    unsigned short* W0lo = (unsigned short*)(ws + off); off = al(off + 128 * 128 * 2);
    unsigned short* W1hi = (unsigned short*)(ws + off); off = al(off + 128 * 128 * 2);
    unsigned short* W1lo = (unsigned short*)(ws + off); off = al(off + 128 * 128 * 2);
    unsigned short* Wshi = (unsigned short*)(ws + off); off = al(off + 128 * 128 * 2);
    unsigned short* Wslo = (unsigned short*)(ws + off); off = al(off + 128 * 128 * 2);
    unsigned short* W2hi = (unsigned short*)(ws + off); off = al(off + 128 * 64 * 2);
    unsigned short* W2lo = (unsigned short*)(ws + off); off = al(off + 128 * 64 * 2);
    (void)ws_size; (void)n_in; (void)out_size;

    hipMemsetAsync(degi, 0, (size_t)N * 4, stream);
    build_ell_kernel<<<(E + 255) / 256, 256, 0, stream>>>(src, dst, E, degi, ell);
    dinv_kernel<<<(N + 255) / 256, 256, 0, stream>>>(degi, dinv, N);
    split_w_kernel<<<64, 256, 0, stream>>>(W0, W0hi, W0lo, 128);
    split_w_kernel<<<64, 256, 0, stream>>>(W1, W1hi, W1lo, 128);
    split_w_kernel<<<64, 256, 0, stream>>>(Ws, Wshi, Wslo, 128);
    split_w_kernel<<<32, 256, 0, stream>>>(W2, W2hi, W2lo, 64);

    const int gg = (N + 127) / 128;
    const int ga = (N + 3) / 4;

    // layer 0: h1 = relu(agg(x@W0) + b0)
    mfma_gemm_kernel<128, true, false><<<gg, 256, 0, stream>>>(
        x, nullptr, nullptr, W0hi, W0lo, nullptr, pA, N);
    agg_kernel<128, 0><<<ga, 256, 0, stream>>>(
        pA, ell, degi, dinv, b0, nullptr, (unsigned*)pBhi, (unsigned*)pBlo, nullptr, N);

    // layer 1: h2 = relu(agg(h1@W1) + b1) + (h1@Ws + bs)
    mfma_gemm_kernel<128, false, true><<<gg, 256, 0, stream>>>(
        nullptr, pBhi, pBlo, Wshi, Wslo, bs, pC, N);
    mfma_gemm_kernel<128, false, false><<<gg, 256, 0, stream>>>(
        nullptr, pBhi, pBlo, W1hi, W1lo, nullptr, pA, N);
    agg_kernel<128, 1><<<ga, 256, 0, stream>>>(
        pA, ell, degi, dinv, b1, pC, (unsigned*)pBhi, (unsigned*)pBlo, nullptr, N);

    // output layer: out = agg(h2@W2) + b2   (F=64, fp32 out)
    mfma_gemm_kernel<64, false, false><<<gg, 256, 0, stream>>>(
        nullptr, pBhi, pBlo, W2hi, W2lo, nullptr, pA, N);
    agg_kernel<64, 2><<<ga, 256, 0, stream>>>(
        pA, ell, degi, dinv, b2, nullptr, nullptr, nullptr, (float*)d_out, N);
}

// Round 5
// 372.724 us; speedup vs baseline: 1.9055x; 1.2451x over previous
//
#include <hip/hip_runtime.h>

#define ELLW 64          // max in-degree capacity (Poisson(16): P(deg>=64) ~ 2e-18)
#define BSHIFT 9         // nodes per bucket = 512
#define BNODES 512
#define NBUCK  256       // compile-time cap (supports N <= 131072)
#define BCAP   12288     // edge capacity per bucket (mean 8192, +45 sigma)

typedef __attribute__((ext_vector_type(8))) short short8v;  // 8 bf16 (4 VGPR)
typedef __attribute__((ext_vector_type(4))) float f32x4;    // MFMA accumulator

__device__ inline unsigned short bf16_rne(float x) {
    unsigned u = __float_as_uint(x);
    u += 0x7FFFu + ((u >> 16) & 1u);
    return (unsigned short)(u >> 16);
}
__device__ inline float bf16_to_f32(unsigned short h) {
    return __uint_as_float(((unsigned)h) << 16);
}

// ---------------------------------------------------------------------------
// Pass 1: partition edges into dst-range buckets (LDS-staged, rank-remember).
// ---------------------------------------------------------------------------
__global__ __launch_bounds__(256) void partition_kernel(
    const int* __restrict__ src, const int* __restrict__ dst, int E,
    uint2* __restrict__ part, int* __restrict__ gtail)
{
    __shared__ int scnt[NBUCK];
    __shared__ int sbase[NBUCK];
    const int t = threadIdx.x;
    #pragma unroll
    for (int i = t; i < NBUCK; i += 256) scnt[i] = 0;
    __syncthreads();

    const int e0 = blockIdx.x * 2048;
    int sarr[8], darr[8], rk[8];
    #pragma unroll
    for (int i = 0; i < 8; ++i) {
        int e = e0 + t + i * 256;
        if (e < E) {
            sarr[i] = src[e];
            darr[i] = dst[e];
            rk[i] = atomicAdd(&scnt[darr[i] >> BSHIFT], 1);
        }
    }
    __syncthreads();
    for (int i = t; i < NBUCK; i += 256)
        sbase[i] = scnt[i] ? atomicAdd(&gtail[i], scnt[i]) : 0;
    __syncthreads();
    #pragma unroll
    for (int i = 0; i < 8; ++i) {
        int e = e0 + t + i * 256;
        if (e < E) {
            int b = darr[i] >> BSHIFT;
            int p = sbase[b] + rk[i];
            if (p < BCAP)
                part[(size_t)b * BCAP + p] = make_uint2((unsigned)sarr[i], (unsigned)darr[i]);
        }
    }
}

// ---------------------------------------------------------------------------
// Pass 2: build each bucket's ELL slab entirely in LDS (atomics + scatter in
// LDS), then stream out coalesced. Also writes degi + dinv (folded).
// LDS: 512*64*4 + 512*4 = 130 KB -> 1 block/CU.
// ---------------------------------------------------------------------------
__global__ __launch_bounds__(512) void ell_bucket_kernel(
    const uint2* __restrict__ part, const int* __restrict__ gcnt,
    int* __restrict__ degi, float* __restrict__ dinv,
    int* __restrict__ ell, int n)
{
    __shared__ int sdeg[BNODES];
    __shared__ int sell[BNODES * ELLW];

    const int b = blockIdx.x;
    const int t = threadIdx.x;
    sdeg[t] = 0;
    __syncthreads();

    int cnt = gcnt[b];
    if (cnt > BCAP) cnt = BCAP;
    const uint2* ep = part + (size_t)b * BCAP;
    for (int i = t; i < cnt; i += 512) {
        uint2 e = ep[i];
        int dl = (int)(e.y & (BNODES - 1));
        int pos = atomicAdd(&sdeg[dl], 1);
        if (pos < ELLW) sell[dl * ELLW + pos] = (int)e.x;
    }
    __syncthreads();

    const int node0 = b << BSHIFT;
    const int node = node0 + t;
    if (node < n) {
        int d = sdeg[t];
        degi[node] = d;
        dinv[node] = rsqrtf((float)d + 1.0f);
    }
    // coalesced int4 copy of the full slab (entries beyond deg are garbage,
    // never read: agg reads only lanes < min(deg, ELLW))
    for (int f4 = t; f4 < BNODES * ELLW / 4; f4 += 512) {
        int nd = node0 + (f4 >> 4);
        if (nd < n) {
            int4 v = *(const int4*)&sell[f4 * 4];
            *(int4*)&ell[(size_t)node0 * ELLW + f4 * 4] = v;
        }
    }
}

// ---------------------------------------------------------------------------
// One-time W preprocess (all four weights in one launch): split fp32 W[128][F]
// into bf16 hi/lo planes, stored TRANSPOSED [F][128].
// ---------------------------------------------------------------------------
__global__ __launch_bounds__(256) void split_all_w_kernel(
    const float* __restrict__ W0, const float* __restrict__ W1,
    const float* __restrict__ Ws, const float* __restrict__ W2,
    unsigned short* __restrict__ W0hi, unsigned short* __restrict__ W0lo,
    unsigned short* __restrict__ W1hi, unsigned short* __restrict__ W1lo,
    unsigned short* __restrict__ Wshi, unsigned short* __restrict__ Wslo,
    unsigned short* __restrict__ W2hi, unsigned short* __restrict__ W2lo)
{
    int id = blockIdx.x * 256 + threadIdx.x;    // 3*16384 + 8192 = 57344 total
    const float* W; unsigned short *Whi, *Wlo; int F, base;
    if (id < 16384)      { W = W0; Whi = W0hi; Wlo = W0lo; F = 128; base = 0; }
    else if (id < 32768) { W = W1; Whi = W1hi; Wlo = W1lo; F = 128; base = 16384; }
    else if (id < 49152) { W = Ws; Whi = Wshi; Wlo = Wslo; F = 128; base = 32768; }
    else if (id < 57344) { W = W2; Whi = W2hi; Wlo = W2lo; F = 64;  base = 49152; }
    else return;
    int l = id - base;
    int k = l / F, c = l % F;
    float x = W[l];
    unsigned short hi = bf16_rne(x);
    Whi[c * 128 + k] = hi;
    Wlo[c * 128 + k] = bf16_rne(x - bf16_to_f32(hi));
}

// ---------------------------------------------------------------------------
// LDS-free split-bf16 MFMA GEMM: out_bf16[N x F] = A[N x 128] @ W[128 x F] (+bias)
// 3-term: Ahi*Bhi + Ahi*Blo + Alo*Bhi, fp32 accum. Fragments straight from
// global (A tile 64KB and W 32KB are L1/L2-hot). 256 thr = 4 waves.
// ---------------------------------------------------------------------------
template<int F, bool AFP32, bool BIAS>
__global__ __launch_bounds__(256) void mfma_gemm_kernel(
    const float* __restrict__ Af,
    const unsigned short* __restrict__ Ahi, const unsigned short* __restrict__ Alo,
    const unsigned short* __restrict__ BhiT, const unsigned short* __restrict__ BloT,
    const float* __restrict__ bias, unsigned short* __restrict__ out, int nrows)
{
    constexpr int WM = (F == 128) ? 2 : 4;
    constexpr int MF = 128 / (WM * 16);
    constexpr int CG = 4;

    const int t    = threadIdx.x;
    const int lane = t & 63;
    const int wv   = t >> 6;
    const int wm   = (F == 128) ? (wv >> 1) : wv;
    const int wn   = (F == 128) ? (wv & 1)  : 0;
    const int l15  = lane & 15;
    const int lg   = lane >> 4;
    const int row0 = blockIdx.x * 128;

    f32x4 acc[MF][CG];
    #pragma unroll
    for (int mf = 0; mf < MF; ++mf)
        #pragma unroll
        for (int cg = 0; cg < CG; ++cg)
            acc[mf][cg] = (f32x4){0.f, 0.f, 0.f, 0.f};

    #pragma unroll
    for (int kk = 0; kk < 4; ++kk) {
        short8v ah[MF], al[MF];
        #pragma unroll
        for (int mf = 0; mf < MF; ++mf) {
            int row = row0 + wm * (MF * 16) + mf * 16 + l15;
            int rl  = row < nrows ? row : 0;
            size_t ao = (size_t)rl * 128 + kk * 32 + lg * 8;
            if constexpr (AFP32) {
                const float* p = &Af[ao];
                float4 v0 = *(const float4*)p;
                float4 v1 = *(const float4*)(p + 4);
                float xs[8] = {v0.x, v0.y, v0.z, v0.w, v1.x, v1.y, v1.z, v1.w};
                short8v h, l;
                #pragma unroll
                for (int j = 0; j < 8; ++j) {
                    unsigned short hb = bf16_rne(xs[j]);
                    h[j] = (short)hb;
                    l[j] = (short)bf16_rne(xs[j] - bf16_to_f32(hb));
                }
                ah[mf] = h; al[mf] = l;
            } else {
                ah[mf] = *(const short8v*)&Ahi[ao];
                al[mf] = *(const short8v*)&Alo[ao];
            }
        }
        #pragma unroll
        for (int cg = 0; cg < CG; ++cg) {
            int col = wn * 64 + cg * 16 + l15;
            size_t bo = (size_t)col * 128 + kk * 32 + lg * 8;
            short8v bh = *(const short8v*)&BhiT[bo];
            short8v bl = *(const short8v*)&BloT[bo];
            #pragma unroll
            for (int mf = 0; mf < MF; ++mf) {
                acc[mf][cg] = __builtin_amdgcn_mfma_f32_16x16x32_bf16(ah[mf], bh, acc[mf][cg], 0, 0, 0);
                acc[mf][cg] = __builtin_amdgcn_mfma_f32_16x16x32_bf16(ah[mf], bl, acc[mf][cg], 0, 0, 0);
                acc[mf][cg] = __builtin_amdgcn_mfma_f32_16x16x32_bf16(al[mf], bh, acc[mf][cg], 0, 0, 0);
            }
        }
    }

    // epilogue: C/D layout col=lane&15, row=(lane>>4)*4+reg; write bf16
    #pragma unroll
    for (int cg = 0; cg < CG; ++cg) {
        int col = wn * 64 + cg * 16 + l15;
        float bv = BIAS ? bias[col] : 0.f;
        #pragma unroll
        for (int mf = 0; mf < MF; ++mf) {
            int rbase = row0 + wm * (MF * 16) + mf * 16 + lg * 4;
            #pragma unroll
            for (int r = 0; r < 4; ++r) {
                int row = rbase + r;
                if (row < nrows)
                    out[(size_t)row * F + col] = bf16_rne(acc[mf][cg][r] + bv);
            }
        }
    }
}

// ---------------------------------------------------------------------------
// Aggregation over bf16 rows, one wave per node, 8-way unrolled gather.
//   r = dinv_i * ( sum_j dinv_j*hw_j + dinv_i*hw_i ) + bias
// MODE 0: relu(r)        -> bf16 hi/lo planes   (h1)
// MODE 1: relu(r) + skip -> bf16 hi/lo planes   (h2)
// MODE 2: r              -> fp32 d_out          (F=64 output layer)
// ---------------------------------------------------------------------------
template<int F, int MODE>
__global__ __launch_bounds__(256) void agg_kernel(
    const unsigned short* __restrict__ hw, const int* __restrict__ ell,
    const int* __restrict__ degi, const float* __restrict__ dinv,
    const float* __restrict__ bias, const unsigned short* __restrict__ skip,
    unsigned* __restrict__ outHi, unsigned* __restrict__ outLo,
    float* __restrict__ outF, int n)
{
    constexpr int VEC = F / 64;
    constexpr int UNR = 8;
    const int lane = threadIdx.x & 63;
    const int node = blockIdx.x * 4 + (threadIdx.x >> 6);
    if (node >= n) return;

    const int deg  = degi[node];
    const int kmax = deg < ELLW ? deg : ELLW;
    const float di = dinv[node];

    int   jpre = 0;
    float vpre = 0.f;
    if (lane < kmax) {
        jpre = ell[node * ELLW + lane];
        vpre = dinv[jpre];
    }

    float acc[4][VEC];
    #pragma unroll
    for (int u = 0; u < 4; ++u)
        #pragma unroll
        for (int v = 0; v < VEC; ++v) acc[u][v] = 0.f;

    if constexpr (VEC == 2) {
        unsigned p = *(const unsigned*)&hw[(size_t)node * F + lane * 2];
        acc[0][0] = bf16_to_f32((unsigned short)(p & 0xFFFF)) * di;
        acc[0][1] = bf16_to_f32((unsigned short)(p >> 16)) * di;
    } else {
        acc[0][0] = bf16_to_f32(hw[(size_t)node * F + lane]) * di;
    }

    const int kceil = (kmax + UNR - 1) & ~(UNR - 1);
    for (int k = 0; k < kceil; k += UNR) {
        int   jj[UNR];
        float vv[UNR];
        #pragma unroll
        for (int u = 0; u < UNR; ++u) {
            jj[u] = __shfl(jpre, k + u);
            vv[u] = __shfl(vpre, k + u);
        }
        if constexpr (VEC == 2) {
            unsigned h[UNR];
            #pragma unroll
            for (int u = 0; u < UNR; ++u)
                h[u] = *(const unsigned*)&hw[(size_t)jj[u] * F + lane * 2];
            #pragma unroll
            for (int u = 0; u < UNR; ++u) {
                acc[u & 3][0] += bf16_to_f32((unsigned short)(h[u] & 0xFFFF)) * vv[u];
                acc[u & 3][1] += bf16_to_f32((unsigned short)(h[u] >> 16)) * vv[u];
            }
        } else {
            unsigned short h[UNR];
            #pragma unroll
            for (int u = 0; u < UNR; ++u)
                h[u] = hw[(size_t)jj[u] * F + lane];
            #pragma unroll
            for (int u = 0; u < UNR; ++u)
                acc[u & 3][0] += bf16_to_f32(h[u]) * vv[u];
        }
    }

    float r[VEC];
    #pragma unroll
    for (int v = 0; v < VEC; ++v) {
        float s = (acc[0][v] + acc[1][v]) + (acc[2][v] + acc[3][v]);
        r[v] = s * di + bias[lane * VEC + v];
    }

    if constexpr (MODE == 2) {
        outF[(size_t)node * F + lane] = r[0];
    } else {
        #pragma unroll
        for (int v = 0; v < VEC; ++v) {
            r[v] = fmaxf(r[v], 0.f);
            if (MODE == 1) {
                unsigned sp = *(const unsigned*)&skip[(size_t)node * F + lane * 2];
                float sv = (v == 0) ? bf16_to_f32((unsigned short)(sp & 0xFFFF))
                                    : bf16_to_f32((unsigned short)(sp >> 16));
                r[v] += sv;
            }
        }
        unsigned short h0 = bf16_rne(r[0]), h1 = bf16_rne(r[1]);
        unsigned short l0 = bf16_rne(r[0] - bf16_to_f32(h0));
        unsigned short l1 = bf16_rne(r[1] - bf16_to_f32(h1));
        size_t o = (size_t)node * (F / 2) + lane;
        outHi[o] = (unsigned)h0 | ((unsigned)h1 << 16);
        outLo[o] = (unsigned)l0 | ((unsigned)l1 << 16);
    }
}

// ---------------------------------------------------------------------------
extern "C" void kernel_launch(void* const* d_in, const int* in_sizes, int n_in,
                              void* d_out, int out_size, void* d_ws, size_t ws_size,
                              hipStream_t stream)
{
    const float* x  = (const float*)d_in[0];
    const int*   ei = (const int*)  d_in[1];
    const float* W0 = (const float*)d_in[2];
    const float* b0 = (const float*)d_in[3];
    const float* W1 = (const float*)d_in[4];
    const float* b1 = (const float*)d_in[5];
    const float* W2 = (const float*)d_in[6];
    const float* b2 = (const float*)d_in[7];
    const float* Ws = (const float*)d_in[8];
    const float* bs = (const float*)d_in[9];

    const int N = in_sizes[0] / 128;
    const int E = in_sizes[1] / 2;
    const int* src = ei;
    const int* dst = ei + E;

    char* ws = (char*)d_ws;
    auto al = [](size_t v) { return (v + 255) & ~size_t(255); };
    size_t off = 0;
    int*   degi  = (int*)  (ws + off); off = al(off + (size_t)N * 4);
    float* dinv  = (float*)(ws + off); off = al(off + (size_t)N * 4);
    int*   gtail = (int*)  (ws + off); off = al(off + NBUCK * 4);
    int*   ell   = (int*)  (ws + off); off = al(off + (size_t)N * ELLW * 4);
    uint2* part  = (uint2*)(ws + off); off = al(off + (size_t)NBUCK * BCAP * 8);
    unsigned short* pA   = (unsigned short*)(ws + off); off = al(off + (size_t)N * 128 * 2);
    unsigned short* pBhi = (unsigned short*)(ws + off); off = al(off + (size_t)N * 128 * 2);
    unsigned short* pBlo = (unsigned short*)(ws + off); off = al(off + (size_t)N * 128 * 2);
    unsigned short* pC   = (unsigned short*)(ws + off); off = al(off + (size_t)N * 128 * 2);
    unsigned short* W0hi = (unsigned short*)(ws + off); off = al(off + 128 * 128 * 2);
    unsigned short* W0lo = (unsigned short*)(ws + off); off = al(off + 128 * 128 * 2);
    unsigned short* W1hi = (unsigned short*)(ws + off); off = al(off + 128 * 128 * 2);
    unsigned short* W1lo = (unsigned short*)(ws + off); off = al(off + 128 * 128 * 2);
    unsigned short* Wshi = (unsigned short*)(ws + off); off = al(off + 128 * 128 * 2);
    unsigned short* Wslo = (unsigned short*)(ws + off); off = al(off + 128 * 128 * 2);
    unsigned short* W2hi = (unsigned short*)(ws + off); off = al(off + 128 * 64 * 2);
    unsigned short* W2lo = (unsigned short*)(ws + off); off = al(off + 128 * 64 * 2);
    (void)ws_size; (void)n_in; (void)out_size;

    hipMemsetAsync(gtail, 0, NBUCK * 4, stream);
    partition_kernel<<<(E + 2047) / 2048, 256, 0, stream>>>(src, dst, E, part, gtail);
    ell_bucket_kernel<<<(N + BNODES - 1) / BNODES, 512, 0, stream>>>(
        part, gtail, degi, dinv, ell, N);
    split_all_w_kernel<<<224, 256, 0, stream>>>(
        W0, W1, Ws, W2, W0hi, W0lo, W1hi, W1lo, Wshi, Wslo, W2hi, W2lo);

    const int gg = (N + 127) / 128;
    const int ga = (N + 3) / 4;

    // layer 0: h1 = relu(agg(x@W0) + b0)
    mfma_gemm_kernel<128, true, false><<<gg, 256, 0, stream>>>(
        x, nullptr, nullptr, W0hi, W0lo, nullptr, pA, N);
    agg_kernel<128, 0><<<ga, 256, 0, stream>>>(
        pA, ell, degi, dinv, b0, nullptr, (unsigned*)pBhi, (unsigned*)pBlo, nullptr, N);

    // layer 1: h2 = relu(agg(h1@W1) + b1) + (h1@Ws + bs)
    mfma_gemm_kernel<128, false, true><<<gg, 256, 0, stream>>>(
        nullptr, pBhi, pBlo, Wshi, Wslo, bs, pC, N);
    mfma_gemm_kernel<128, false, false><<<gg, 256, 0, stream>>>(
        nullptr, pBhi, pBlo, W1hi, W1lo, nullptr, pA, N);
    agg_kernel<128, 1><<<ga, 256, 0, stream>>>(
        pA, ell, degi, dinv, b1, pC, (unsigned*)pBhi, (unsigned*)pBlo, nullptr, N);

    // output layer: out = agg(h2@W2) + b2   (F=64, fp32 out)
    mfma_gemm_kernel<64, false, false><<<gg, 256, 0, stream>>>(
        nullptr, pBhi, pBlo, W2hi, W2lo, nullptr, pA, N);
    agg_kernel<64, 2><<<ga, 256, 0, stream>>>(
        pA, ell, degi, dinv, b2, nullptr, nullptr, nullptr, (float*)d_out, N);
}